// Round 10
// baseline (1734.213 us; speedup 1.0000x reference)
//
#include <hip/hip_runtime.h>
#include <hip/hip_bf16.h>

#define NTOK   8192
#define HDIM   1024
#define NEXP   8
#define IDIM   2048
#define TOTAL  (NTOK*2)
#define MAXT   136   // max row-tiles: sum ceil(cnt_e/128) <= 128+8

typedef short bf16x8 __attribute__((ext_vector_type(8)));
typedef float f32x4  __attribute__((ext_vector_type(4)));

__device__ __forceinline__ unsigned short f2bf(float f) {
  __hip_bfloat16 h = __float2bfloat16(f);
  return *reinterpret_cast<unsigned short*>(&h);
}
__device__ __forceinline__ float bf2f(unsigned short u) {
  __hip_bfloat16 h = *reinterpret_cast<__hip_bfloat16*>(&u);
  return __bfloat162float(h);
}

// async global->LDS, 16B/lane. LDS base wave-uniform; HW writes base + lane*16.
// Global source address is per-lane (token gather + swizzle folded into source).
__device__ __forceinline__ void lds_load16(const unsigned short* gsrc, unsigned short* lds_base_uniform) {
  __builtin_amdgcn_global_load_lds(
      (const __attribute__((address_space(1))) unsigned int*)gsrc,
      (__attribute__((address_space(3))) unsigned int*)lds_base_uniform,
      16, 0, 0);
}

// ---------------- router: one wave per token ----------------
__global__ void router_kernel(const float* __restrict__ x, const float* __restrict__ Wr,
                              int* __restrict__ sel, float* __restrict__ selw,
                              int* __restrict__ counts) {
  int t = blockIdx.x * 4 + (threadIdx.x >> 6);
  int lane = threadIdx.x & 63;
  float acc[NEXP];
#pragma unroll
  for (int e = 0; e < NEXP; ++e) acc[e] = 0.f;
  const float* xr = x + (size_t)t * HDIM;
  for (int h = lane; h < HDIM; h += 64) {
    float xv = xr[h];
    const float* wr = Wr + h * NEXP;
#pragma unroll
    for (int e = 0; e < NEXP; ++e) acc[e] += xv * wr[e];
  }
#pragma unroll
  for (int off = 32; off > 0; off >>= 1) {
#pragma unroll
    for (int e = 0; e < NEXP; ++e) acc[e] += __shfl_xor(acc[e], off, 64);
  }
  if (lane == 0) {
    int i0 = 0; float v0 = acc[0];
#pragma unroll
    for (int e = 1; e < NEXP; ++e) if (acc[e] > v0) { v0 = acc[e]; i0 = e; }
    int i1 = -1; float v1 = -1e30f;
#pragma unroll
    for (int e = 0; e < NEXP; ++e) if (e != i0 && acc[e] > v1) { v1 = acc[e]; i1 = e; }
    float e1 = expf(v1 - v0);
    float w0 = 1.f / (1.f + e1);
    float w1 = e1 / (1.f + e1);
    sel[t*2] = i0; sel[t*2+1] = i1;
    selw[t*2] = w0; selw[t*2+1] = w1;
    atomicAdd(&counts[i0], 1);
    atomicAdd(&counts[i1], 1);
  }
}

// offsets + compact tile table (no dead blocks in the GEMM grids)
__global__ void prefix_kernel(const int* __restrict__ counts, int* __restrict__ offsets,
                              int* __restrict__ cursor, int* __restrict__ tile_e,
                              int* __restrict__ tile_r) {
  if (threadIdx.x == 0) {
    int s = 0;
    for (int e = 0; e < NEXP; ++e) { offsets[e] = s; cursor[e] = s; s += counts[e]; }
    offsets[NEXP] = s;
    int nt = 0;
    for (int e = 0; e < NEXP; ++e)
      for (int r0 = 0; r0 < counts[e]; r0 += 128) { tile_e[nt] = e; tile_r[nt] = r0; ++nt; }
    for (; nt < MAXT; ++nt) { tile_e[nt] = -1; tile_r[nt] = 0; }
  }
}

__global__ void scatter_kernel(const int* __restrict__ sel, const float* __restrict__ selw,
                               int* __restrict__ cursor, int* __restrict__ token_ids,
                               float* __restrict__ gates) {
  int t = blockIdx.x * 256 + threadIdx.x;
  if (t >= NTOK) return;
#pragma unroll
  for (int k = 0; k < 2; ++k) {
    int e = sel[t*2+k];
    int p = atomicAdd(&cursor[e], 1);
    token_ids[p] = t;
    gates[p] = selw[t*2+k];
  }
}

// x [NTOK][1024] fp32 -> Xs [NTOK][2048] bf16 (hi 0..1023 | lo 1024..2047)
__global__ void xsplit_kernel(const float* __restrict__ x, unsigned short* __restrict__ Xs) {
  int t = blockIdx.x;
  const float4* src = reinterpret_cast<const float4*>(x + (size_t)t * HDIM);
  float4 v = src[threadIdx.x];
  unsigned short h0 = f2bf(v.x), h1 = f2bf(v.y), h2 = f2bf(v.z), h3 = f2bf(v.w);
  ushort4 hi = { h0, h1, h2, h3 };
  ushort4 lo = { f2bf(v.x - bf2f(h0)), f2bf(v.y - bf2f(h1)),
                 f2bf(v.z - bf2f(h2)), f2bf(v.w - bf2f(h3)) };
  *reinterpret_cast<ushort4*>(Xs + (size_t)t*2*HDIM + threadIdx.x*4) = hi;
  *reinterpret_cast<ushort4*>(Xs + (size_t)t*2*HDIM + HDIM + threadIdx.x*4) = lo;
}

// W [E][R][C] fp32 -> WT [E][C][2R] bf16, WT[e][c][r]=hi(W[e][r][c]), WT[e][c][R+r]=lo
__global__ void split_transpose_kernel(const float* __restrict__ W, unsigned short* __restrict__ WT,
                                       int R, int C) {
  int e = blockIdx.z;
  int c0 = blockIdx.x * 64, r0 = blockIdx.y * 64;
  __shared__ unsigned short hiT[64][65];
  __shared__ unsigned short loT[64][65];
  int tx = threadIdx.x & 63, ty = threadIdx.x >> 6;
  const float* src = W + ((size_t)e * R + r0) * C + c0;
#pragma unroll
  for (int rr = 0; rr < 16; ++rr) {
    int r_l = ty * 16 + rr;
    float v = src[(size_t)r_l * C + tx];
    unsigned short h = f2bf(v);
    hiT[tx][r_l] = h;
    loT[tx][r_l] = f2bf(v - bf2f(h));
  }
  __syncthreads();
  unsigned short* dst = WT + ((size_t)e * C + c0) * (size_t)(2*R) + r0;
#pragma unroll
  for (int ww = 0; ww < 16; ++ww) {
    int c_l = ty * 16 + ww;
    dst[(size_t)c_l * (2*R) + tx]     = hiT[c_l][tx];
    dst[(size_t)c_l * (2*R) + R + tx] = loT[c_l][tx];
  }
}

// ---------------- GEMM1: act = silu(Xs@W1g)*(Xs@W1u), split-K'=3*1024, BK=32, 2-phase ----------------
// Block 128 rows x 128 j-cols; wave 64x64x2. LDS rows 32 elems (64B), dbuf.
// Granule swizzle: 16B slot g2 of row r holds global granule g2^(r&3).
__global__ __launch_bounds__(256, 2)
void gemm1_kernel(const unsigned short* __restrict__ Xs,
                  const unsigned short* __restrict__ W1sT,
                  unsigned short* __restrict__ actS,
                  const int* __restrict__ offsets,
                  const int* __restrict__ token_ids,
                  const int* __restrict__ tile_e,
                  const int* __restrict__ tile_r) {
  int e = tile_e[blockIdx.x];
  if (e < 0) return;
  int r0 = tile_r[blockIdx.x];
  int off = offsets[e];
  int cnt = offsets[e+1] - off;
  int j0 = blockIdx.y * 128;

  __shared__ unsigned short As[2*128*32];   // 16KB
  __shared__ unsigned short Bg[2*128*32];   // 16KB
  __shared__ unsigned short Bu[2*128*32];   // 16KB

  int tid = threadIdx.x;
  int lane = tid & 63, wv = tid >> 6;
  int l15 = lane & 15, lq = lane >> 4;
  int lr = lane >> 2;         // row within 16-row issue
  int g2 = lane & 3;          // dest granule (4 per 64B row)
  int wr = wv >> 1;           // wave row-half
  int wc = wv & 1;            // wave col-half

  const unsigned short* w1e = W1sT + (size_t)e * 4096 * 2048;

  const unsigned short* srcA[2]; unsigned short* dstA[2];
  const unsigned short* srcBg[2]; const unsigned short* srcBu[2];
  unsigned short* dstBg[2]; unsigned short* dstBu[2];
#pragma unroll
  for (int i = 0; i < 2; ++i) {
    int rowt = wv*32 + i*16 + lr;
    int gp = off + r0 + rowt; if (gp > TOTAL-1) gp = TOTAL-1;
    int tok = token_ids[gp];
    int sg = g2 ^ (rowt & 3);
    srcA[i]  = Xs + (size_t)tok*2048 + sg*8;
    dstA[i]  = As + wv*1024 + i*512;
    srcBg[i] = w1e + (size_t)(j0 + rowt)*2048 + sg*8;
    srcBu[i] = w1e + (size_t)(IDIM + j0 + rowt)*2048 + sg*8;
    dstBg[i] = Bg + wv*1024 + i*512;
    dstBu[i] = Bu + wv*1024 + i*512;
  }

#define G1_STAGE(ks, par) do {                                          \
    int s_ = (ks) >> 5; int k0_ = ((ks) & 31) << 5;                     \
    int aoff_ = ((s_ == 1) ? HDIM : 0) + k0_;                           \
    int boff_ = ((s_ == 2) ? HDIM : 0) + k0_;                           \
    int po_ = (par) * 4096;                                             \
    _Pragma("unroll")                                                   \
    for (int i_ = 0; i_ < 2; ++i_) {                                    \
      lds_load16(srcA[i_]  + aoff_, dstA[i_]  + po_);                   \
      lds_load16(srcBg[i_] + boff_, dstBg[i_] + po_);                   \
      lds_load16(srcBu[i_] + boff_, dstBu[i_] + po_);                   \
    }                                                                   \
  } while (0)

  f32x4 accg[4][4], accu[4][4];
#pragma unroll
  for (int m = 0; m < 4; ++m)
#pragma unroll
    for (int n = 0; n < 4; ++n) {
      accg[m][n] = f32x4{0.f, 0.f, 0.f, 0.f};
      accu[m][n] = f32x4{0.f, 0.f, 0.f, 0.f};
    }

  int gg = (lq ^ (l15 & 3)) * 8;   // de-swizzled granule offset (elems)

  G1_STAGE(0, 0);
  int cur = 0;
  for (int ks = 0; ks < 96; ++ks) {
    __syncthreads();                       // buf[cur] staged; prev reads done
    if (ks + 1 < 96) G1_STAGE(ks + 1, cur ^ 1);

    int po = cur * 4096;
    bf16x8 af[4], bgf[4], buf2[4];
#pragma unroll
    for (int m = 0; m < 4; ++m)
      af[m] = *reinterpret_cast<const bf16x8*>(&As[po + (wr*64 + m*16 + l15)*32 + gg]);
#pragma unroll
    for (int n = 0; n < 4; ++n) {
      bgf[n]  = *reinterpret_cast<const bf16x8*>(&Bg[po + (wc*64 + n*16 + l15)*32 + gg]);
      buf2[n] = *reinterpret_cast<const bf16x8*>(&Bu[po + (wc*64 + n*16 + l15)*32 + gg]);
    }
#pragma unroll
    for (int m = 0; m < 4; ++m)
#pragma unroll
      for (int n = 0; n < 4; ++n) {
        accg[m][n] = __builtin_amdgcn_mfma_f32_16x16x32_bf16(af[m], bgf[n], accg[m][n], 0, 0, 0);
        accu[m][n] = __builtin_amdgcn_mfma_f32_16x16x32_bf16(af[m], buf2[n], accu[m][n], 0, 0, 0);
      }
    cur ^= 1;
  }
#undef G1_STAGE

#pragma unroll
  for (int m = 0; m < 4; ++m) {
#pragma unroll
    for (int rr = 0; rr < 4; ++rr) {
      int lrow = r0 + wr*64 + m*16 + lq*4 + rr;
      if (lrow < cnt) {
        size_t prow = (size_t)(off + lrow);
#pragma unroll
        for (int n = 0; n < 4; ++n) {
          float gte = accg[m][n][rr], u = accu[m][n][rr];
          float a = (gte / (1.f + expf(-gte))) * u;   // silu(g)*u
          unsigned short hh = f2bf(a);
          unsigned short ll = f2bf(a - bf2f(hh));
          int col = j0 + wc*64 + n*16 + l15;
          actS[prow*4096 + col]        = hh;
          actS[prow*4096 + IDIM + col] = ll;
        }
      }
    }
  }
}

// ---------------- GEMM2: out += g * (act @ W2), split-K'=3*2048, BK=32, 2-phase ----------------
// Block 128 rows x 256 cols; wave 64x128.
__global__ __launch_bounds__(256, 2)
void gemm2_kernel(const unsigned short* __restrict__ actS,
                  const unsigned short* __restrict__ W2sT,
                  const int* __restrict__ offsets,
                  const int* __restrict__ token_ids,
                  const float* __restrict__ gates,
                  float* __restrict__ out,
                  const int* __restrict__ tile_e,
                  const int* __restrict__ tile_r) {
  int e = tile_e[blockIdx.x];
  if (e < 0) return;
  int r0 = tile_r[blockIdx.x];
  int off = offsets[e];
  int cnt = offsets[e+1] - off;
  int c0 = blockIdx.y * 256;

  __shared__ unsigned short As[2*128*32];   // 16KB
  __shared__ unsigned short Bs[2*256*32];   // 32KB

  int tid = threadIdx.x;
  int lane = tid & 63, wv = tid >> 6;
  int l15 = lane & 15, lq = lane >> 4;
  int lr = lane >> 2;
  int g2 = lane & 3;
  int wr = wv >> 1;
  int wc = wv & 1;

  const unsigned short* w2e = W2sT + (size_t)e * 1024 * 4096;

  const unsigned short* srcA[2]; unsigned short* dstA[2];
  const unsigned short* srcB[4]; unsigned short* dstB[4];
#pragma unroll
  for (int i = 0; i < 2; ++i) {
    int rowt = wv*32 + i*16 + lr;
    int gp = off + r0 + rowt; if (gp > TOTAL-1) gp = TOTAL-1;
    int sg = g2 ^ (rowt & 3);
    srcA[i] = actS + (size_t)gp*4096 + sg*8;
    dstA[i] = As + wv*1024 + i*512;
  }
#pragma unroll
  for (int i = 0; i < 4; ++i) {
    int rowt = wv*64 + i*16 + lr;
    int sg = g2 ^ (rowt & 3);
    srcB[i] = w2e + (size_t)(c0 + rowt)*4096 + sg*8;
    dstB[i] = Bs + wv*2048 + i*512;
  }

#define G2_STAGE(ks, par) do {                                          \
    int s_ = (ks) >> 6; int k0_ = ((ks) & 63) << 5;                     \
    int aoff_ = ((s_ == 1) ? IDIM : 0) + k0_;                           \
    int boff_ = ((s_ == 2) ? IDIM : 0) + k0_;                           \
    int poA_ = (par) * 4096; int poB_ = (par) * 8192;                   \
    _Pragma("unroll")                                                   \
    for (int i_ = 0; i_ < 2; ++i_) lds_load16(srcA[i_] + aoff_, dstA[i_] + poA_); \
    _Pragma("unroll")                                                   \
    for (int i_ = 0; i_ < 4; ++i_) lds_load16(srcB[i_] + boff_, dstB[i_] + poB_); \
  } while (0)

  f32x4 acc[4][8];
#pragma unroll
  for (int m = 0; m < 4; ++m)
#pragma unroll
    for (int n = 0; n < 8; ++n) acc[m][n] = f32x4{0.f, 0.f, 0.f, 0.f};

  int gg = (lq ^ (l15 & 3)) * 8;

  G2_STAGE(0, 0);
  int cur = 0;
  for (int ks = 0; ks < 192; ++ks) {
    __syncthreads();
    if (ks + 1 < 192) G2_STAGE(ks + 1, cur ^ 1);

    int poA = cur * 4096, poB = cur * 8192;
    bf16x8 af[4], bfr[8];
#pragma unroll
    for (int m = 0; m < 4; ++m)
      af[m] = *reinterpret_cast<const bf16x8*>(&As[poA + (wr*64 + m*16 + l15)*32 + gg]);
#pragma unroll
    for (int n = 0; n < 8; ++n)
      bfr[n] = *reinterpret_cast<const bf16x8*>(&Bs[poB + (wc*128 + n*16 + l15)*32 + gg]);
#pragma unroll
    for (int m = 0; m < 4; ++m)
#pragma unroll
      for (int n = 0; n < 8; ++n)
        acc[m][n] = __builtin_amdgcn_mfma_f32_16x16x32_bf16(af[m], bfr[n], acc[m][n], 0, 0, 0);
    cur ^= 1;
  }
#undef G2_STAGE

#pragma unroll
  for (int m = 0; m < 4; ++m) {
#pragma unroll
    for (int rr = 0; rr < 4; ++rr) {
      int lrow = r0 + wr*64 + m*16 + lq*4 + rr;
      if (lrow < cnt) {
        int pos = off + lrow;
        int t = token_ids[pos];
        float w = gates[pos];
        float* orow = out + (size_t)t * HDIM;
#pragma unroll
        for (int n = 0; n < 8; ++n)
          atomicAdd(&orow[c0 + wc*128 + n*16 + l15], w * acc[m][n][rr]);
      }
    }
  }
}

extern "C" void kernel_launch(void* const* d_in, const int* in_sizes, int n_in,
                              void* d_out, int out_size, void* d_ws, size_t ws_size,
                              hipStream_t stream) {
  (void)in_sizes; (void)n_in;
  const float* x  = (const float*)d_in[0];
  const float* Wr = (const float*)d_in[1];
  const float* W1 = (const float*)d_in[2];
  const float* W2 = (const float*)d_in[3];
  float* out = (float*)d_out;

  char* ws = (char*)d_ws;
  int*   counts    = (int*)(ws + 0);
  int*   offsets   = (int*)(ws + 64);
  int*   cursor    = (int*)(ws + 128);
  int*   tile_e    = (int*)(ws + 192);     // 136 ints
  int*   tile_r    = (int*)(ws + 768);     // 136 ints
  int*   sel       = (int*)(ws + 4096);
  float* selw      = (float*)(ws + 4096 + 65536);
  int*   token_ids = (int*)(ws + 4096 + 2*65536);
  float* gates     = (float*)(ws + 4096 + 3*65536);
  const size_t XS_OFF   = 266240ULL;
  const size_t W1T_OFF  = XS_OFF  + 33554432ULL;      // Xs:   8192*2048*2   = 32 MB
  const size_t W2T_OFF  = W1T_OFF + 134217728ULL;     // W1sT: 8*4096*2048*2 = 128 MB
  const size_t ACT_OFF  = W2T_OFF + 67108864ULL;      // W2sT: 8*1024*4096*2 = 64 MB
  const size_t REQUIRED = ACT_OFF + 134217728ULL;     // actS: 16384*4096*2  = 128 MB => ~352 MB
  unsigned short* Xs   = (unsigned short*)(ws + XS_OFF);
  unsigned short* W1sT = (unsigned short*)(ws + W1T_OFF);
  unsigned short* W2sT = (unsigned short*)(ws + W2T_OFF);
  unsigned short* actS = (unsigned short*)(ws + ACT_OFF);

  hipMemsetAsync(d_out, 0, (size_t)out_size * sizeof(float), stream);
  if (ws_size < REQUIRED) return;

  hipMemsetAsync(counts, 0, 64, stream);
  router_kernel<<<NTOK/4, 256, 0, stream>>>(x, Wr, sel, selw, counts);
  prefix_kernel<<<1, 64, 0, stream>>>(counts, offsets, cursor, tile_e, tile_r);
  scatter_kernel<<<NTOK/256, 256, 0, stream>>>(sel, selw, cursor, token_ids, gates);
  xsplit_kernel<<<NTOK, 256, 0, stream>>>(x, Xs);
  split_transpose_kernel<<<dim3(64, 16, NEXP), 256, 0, stream>>>(W1, W1sT, 1024, 4096);
  split_transpose_kernel<<<dim3(16, 32, NEXP), 256, 0, stream>>>(W2, W2sT, 2048, 1024);
  gemm1_kernel<<<dim3(MAXT, 16, 1), 256, 0, stream>>>(Xs, W1sT, actS, offsets, token_ids, tile_e, tile_r);
  gemm2_kernel<<<dim3(MAXT, 4, 1), 256, 0, stream>>>(actS, W2sT, offsets, token_ids, gates, out, tile_e, tile_r);
}